// Round 11
// baseline (76.580 us; speedup 1.0000x reference)
//
#include <hip/hip_runtime.h>
#include <math.h>

// Problem constants
#define B_   2
#define C_   32
#define H_   176
#define W_   608
#define HO_  351
#define WO_  1215
#define PLANE_O (HO_ * WO_)          // 426465
#define OUT1_O  (B_ * C_ * PLANE_O)  // 27293760 (mult of 4 -> same alignment)
#define EPS_ 1e-20f
#define NTH  512
#define W4   (W_ / 4)                // 152 float4 per input row
#define HW_  304                     // half-row length (col-parity split)
#define NRLDS 5                      // fused rows staged per block

typedef float f4_t __attribute__((ext_vector_type(4)));
typedef float f2_t __attribute__((ext_vector_type(2)));

__device__ __forceinline__ float softplus_f(float x) {
    return fmaxf(x, 0.0f) + log1pf(expf(-fabsf(x)));
}

// Block = (8-output-row group G, plane). 8 waves, 24.3 KB LDS -> 4 blocks/CU
// (32 waves). 3-phase pipeline: stage(f0..f2); bar; stage(f3..f4) ||
// consume(rows 0..3); bar; consume(rows 4..7). Consume: 2 waves per output
// row (column-split by subwave). NT stores (measured +14us vs cached).
extern "C" __global__ __launch_bounds__(NTH, 8)
void structn_pipe8(const float* __restrict__ d,
                   const float* __restrict__ cd,
                   const float* __restrict__ gy,
                   const float* __restrict__ cgy,
                   const float* __restrict__ wpr,
                   const float* __restrict__ swr,
                   const float* __restrict__ bias,
                   float* __restrict__ out)
{
    __shared__ float s_nE[NRLDS * HW_];   // cgy_f*gy_f, even input cols
    __shared__ float s_nO[NRLDS * HW_];   // odd cols
    __shared__ float s_cE[NRLDS * HW_];   // cgy_f, even cols
    __shared__ float s_cO[NRLDS * HW_];   // odd cols

    const int G     = blockIdx.x;     // 44 groups of 8 output rows
    const int plane = blockIdx.y;     // 64 planes
    const int c     = plane & (C_ - 1);

    // ---- per-channel constants (wave-uniform, in-block) ----
    float sw[9];
#pragma unroll
    for (int k = 0; k < 9; ++k) sw[k] = softplus_f(swr[c * 9 + k]);
    const float wp      = softplus_f(wpr[c]);
    const float inv_wp1 = 1.0f / (wp + 1.0f);
    const float bv      = bias[c];
    const float icd_ee  = 1.0f / (sw[4] + EPS_);
    const float icd_eo  = 1.0f / (sw[3] + sw[5] + EPS_);
    const float icd_oe  = 1.0f / (sw[1] + sw[7] + EPS_);
    const float icd_oo  = 1.0f / (sw[0] + sw[2] + sw[6] + sw[8] + EPS_);

    const int f0 = G * 4;             // first fused row of this block

    const int pbase = plane * (H_ * W_);
    const float* __restrict__ dP  = d   + pbase;
    const float* __restrict__ cdP = cd  + pbase;
    const float* __restrict__ gyP = gy  + pbase;
    const float* __restrict__ cgP = cgy + pbase;

    // ---- staging of local fused rows [j0, j1), guarded vs H ----
    auto stage_rows = [&](int j0, int j1) {
        const int j1c = min(j1, H_ - f0);
        const int ntask = (j1c > j0) ? (j1c - j0) * W4 : 0;
        for (int idx = threadIdx.x; idx < ntask; idx += NTH) {
            const int rf = j0 + idx / W4;
            const int iw = (idx - (rf - j0) * W4) << 2;
            const int iy = f0 + rf;
            const int up = (iy == 0)      ? (H_ - 1) : iy - 1;   // d wraps
            const int dn = (iy == H_ - 1) ? 0        : iy + 1;
            const float mu = (iy > 0)      ? 1.0f : 0.0f;
            const float md = (iy < H_ - 1) ? 1.0f : 0.0f;

            const f4_t du = *(const f4_t*)(dP  + up * W_ + iw);
            const f4_t dd = *(const f4_t*)(dP  + dn * W_ + iw);
            const f4_t cu = *(const f4_t*)(cdP + up * W_ + iw);
            const f4_t cn = *(const f4_t*)(cdP + dn * W_ + iw);
            const f4_t gg = *(const f4_t*)(gyP + iy * W_ + iw);
            const f4_t cg = *(const f4_t*)(cgP + iy * W_ + iw);

            f4_t sn4, sc4;
#pragma unroll
            for (int e = 0; e < 4; ++e) {
                const float cuv = cu[e] * mu;
                const float cnv = cn[e] * md;
                const float cfd = cuv * cuv;
                const float rs  = __builtin_amdgcn_rcpf(fmaf(cuv, du[e], cnv * dd[e]));
                const float gfd = 0.5f * (dd[e] - du[e]) * (cuv + cnv) * rs;
                const float num = fmaf(wp * cg[e], gg[e], cfd * gfd);
                const float den = fmaf(wp, cg[e], cfd);
                sn4[e] = num * inv_wp1;
                sc4[e] = den * inv_wp1;
            }
            const int eo = rf * HW_ + (iw >> 1);   // even -> 8B aligned
            f2_t v;
            v[0] = sn4[0]; v[1] = sn4[2];  *(f2_t*)(s_nE + eo) = v;
            v[0] = sn4[1]; v[1] = sn4[3];  *(f2_t*)(s_nO + eo) = v;
            v[0] = sc4[0]; v[1] = sc4[2];  *(f2_t*)(s_cE + eo) = v;
            v[0] = sc4[1]; v[1] = sc4[3];  *(f2_t*)(s_cO + eo) = v;
        }
    };

    const int w    = threadIdx.x >> 6;
    const int lane = threadIdx.x & 63;

    // ---- consume quarter qi (4 output rows, 2 waves per row) ----
    auto consume_quarter = [&](int qi) {
        const int rr = w >> 1;                 // row within quarter, 0..3
        const int s  = w & 1;                  // column subwave
        const int oy = G * 8 + 4 * qi + rr;
        if (oy >= HO_) return;

        const int p   = rr & 1;                // row parity (8G+4qi even)
        const int lrA = 2 * qi + (rr >> 1);    // local fused row (A)

        const int ro0 = plane * PLANE_O + oy * WO_;
        float* __restrict__ o0 = out + ro0;
        float* __restrict__ o1 = out + OUT1_O + ro0;

        const int h4 = (4 - (ro0 & 3)) & 3;    // head scalars to 16B alignment
        const int n4 = (WO_ - h4) >> 2;        // aligned float4 chunks
        const int q  = h4 & 1;
        const int r  = (h4 >> 1) & 1;

        const float icdC = p ? icd_oe : icd_ee;
        const float icdO = p ? icd_oo : icd_eo;
        const float i0 = q ? icdO : icdC;
        const float i1 = q ? icdC : icdO;

        const float* __restrict__ nAE = s_nE + lrA * HW_;
        const float* __restrict__ nAO = s_nO + lrA * HW_;
        const float* __restrict__ cAE = s_cE + lrA * HW_;
        const float* __restrict__ cAO = s_cO + lrA * HW_;

#define VAL(E, O, j) (((j) & 1) ? (O)[((j) - 1) >> 1] : (E)[(j) >> 1])
        if (p == 0) {
            if (s == 0 && lane < 3) {
                const int ox = (lane < h4) ? lane : (h4 + (n4 << 2) + lane - h4);
                float den, nom, icd;
                if ((ox & 1) == 0) {
                    const int j = ox >> 1;
                    den = VAL(cAE, cAO, j) * sw[4];
                    nom = VAL(nAE, nAO, j) * sw[4];
                    icd = icd_ee;
                } else {
                    const int j = (ox - 1) >> 1;
                    den = VAL(cAE, cAO, j) * sw[5] + VAL(cAE, cAO, j + 1) * sw[3];
                    nom = VAL(nAE, nAO, j) * sw[5] + VAL(nAE, nAO, j + 1) * sw[3];
                    icd = icd_eo;
                }
                o0[ox] = fmaf(0.5f * nom, __builtin_amdgcn_rcpf(den + EPS_), bv);
                o1[ox] = den * icd;
            }
            const float* pa0 = r ? nAO : nAE;
            const float* pa1 = r ? nAE + 1 : nAO;
            const float* pa2 = r ? nAO + 1 : nAE + 1;
            const float* px0 = r ? cAO : cAE;
            const float* px1 = r ? cAE + 1 : cAO;
            const float* px2 = r ? cAO + 1 : cAE + 1;

            for (int k = lane + 64 * s; k < n4; k += 128) {
                const float a0 = pa0[k], a1 = pa1[k], a2 = pa2[k];
                const float x0 = px0[k], x1 = px1[k], x2 = px2[k];
                const float dC0 = x0 * sw[4], dC1 = x1 * sw[4], dC2 = x2 * sw[4];
                const float nC0 = a0 * sw[4], nC1 = a1 * sw[4], nC2 = a2 * sw[4];
                const float dF0 = x0 * sw[5] + x1 * sw[3];
                const float dF1 = x1 * sw[5] + x2 * sw[3];
                const float nF0 = a0 * sw[5] + a1 * sw[3];
                const float nF1 = a1 * sw[5] + a2 * sw[3];

                const float d0 = q ? dF0 : dC0, n0 = q ? nF0 : nC0;
                const float d1 = q ? dC1 : dF0, n1 = q ? nC1 : nF0;
                const float d2 = q ? dF1 : dC1, n2 = q ? nF1 : nC1;
                const float d3 = q ? dC2 : dF1, n3 = q ? nC2 : nF1;

                f4_t gv, qv;
                gv[0] = fmaf(0.5f * n0, __builtin_amdgcn_rcpf(d0 + EPS_), bv);
                gv[1] = fmaf(0.5f * n1, __builtin_amdgcn_rcpf(d1 + EPS_), bv);
                gv[2] = fmaf(0.5f * n2, __builtin_amdgcn_rcpf(d2 + EPS_), bv);
                gv[3] = fmaf(0.5f * n3, __builtin_amdgcn_rcpf(d3 + EPS_), bv);
                qv[0] = d0 * i0; qv[1] = d1 * i1; qv[2] = d2 * i0; qv[3] = d3 * i1;

                const int c0 = h4 + (k << 2);
                __builtin_nontemporal_store(gv, (f4_t*)(o0 + c0));
                __builtin_nontemporal_store(qv, (f4_t*)(o1 + c0));
            }
        } else {
            const float* __restrict__ nBE = nAE + HW_;
            const float* __restrict__ nBO = nAO + HW_;
            const float* __restrict__ cBE = cAE + HW_;
            const float* __restrict__ cBO = cAO + HW_;

            if (s == 0 && lane < 3) {
                const int ox = (lane < h4) ? lane : (h4 + (n4 << 2) + lane - h4);
                float den, nom, icd;
                if ((ox & 1) == 0) {
                    const int j = ox >> 1;
                    den = VAL(cAE, cAO, j) * sw[7] + VAL(cBE, cBO, j) * sw[1];
                    nom = VAL(nAE, nAO, j) * sw[7] + VAL(nBE, nBO, j) * sw[1];
                    icd = icd_oe;
                } else {
                    const int j = (ox - 1) >> 1;
                    den = VAL(cAE, cAO, j) * sw[8] + VAL(cAE, cAO, j + 1) * sw[6]
                        + VAL(cBE, cBO, j) * sw[2] + VAL(cBE, cBO, j + 1) * sw[0];
                    nom = VAL(nAE, nAO, j) * sw[8] + VAL(nAE, nAO, j + 1) * sw[6]
                        + VAL(nBE, nBO, j) * sw[2] + VAL(nBE, nBO, j + 1) * sw[0];
                    icd = icd_oo;
                }
                o0[ox] = fmaf(0.5f * nom, __builtin_amdgcn_rcpf(den + EPS_), bv);
                o1[ox] = den * icd;
            }

            const float* pa0 = r ? nAO : nAE;
            const float* pa1 = r ? nAE + 1 : nAO;
            const float* pa2 = r ? nAO + 1 : nAE + 1;
            const float* px0 = r ? cAO : cAE;
            const float* px1 = r ? cAE + 1 : cAO;
            const float* px2 = r ? cAO + 1 : cAE + 1;
            const float* pb0 = r ? nBO : nBE;
            const float* pb1 = r ? nBE + 1 : nBO;
            const float* pb2 = r ? nBO + 1 : nBE + 1;
            const float* py0 = r ? cBO : cBE;
            const float* py1 = r ? cBE + 1 : cBO;
            const float* py2 = r ? cBO + 1 : cBE + 1;

            for (int k = lane + 64 * s; k < n4; k += 128) {
                const float a0 = pa0[k], a1 = pa1[k], a2 = pa2[k];
                const float x0 = px0[k], x1 = px1[k], x2 = px2[k];
                const float b0 = pb0[k], b1 = pb1[k], b2 = pb2[k];
                const float y0 = py0[k], y1 = py1[k], y2 = py2[k];

                const float dC0 = x0 * sw[7] + y0 * sw[1];
                const float dC1 = x1 * sw[7] + y1 * sw[1];
                const float dC2 = x2 * sw[7] + y2 * sw[1];
                const float nC0 = a0 * sw[7] + b0 * sw[1];
                const float nC1 = a1 * sw[7] + b1 * sw[1];
                const float nC2 = a2 * sw[7] + b2 * sw[1];
                const float dF0 = x0 * sw[8] + x1 * sw[6] + y0 * sw[2] + y1 * sw[0];
                const float dF1 = x1 * sw[8] + x2 * sw[6] + y1 * sw[2] + y2 * sw[0];
                const float nF0 = a0 * sw[8] + a1 * sw[6] + b0 * sw[2] + b1 * sw[0];
                const float nF1 = a1 * sw[8] + a2 * sw[6] + b1 * sw[2] + b2 * sw[0];

                const float d0 = q ? dF0 : dC0, n0 = q ? nF0 : nC0;
                const float d1 = q ? dC1 : dF0, n1 = q ? nC1 : nF0;
                const float d2 = q ? dF1 : dC1, n2 = q ? nF1 : nC1;
                const float d3 = q ? dC2 : dF1, n3 = q ? nC2 : nF1;

                f4_t gv, qv;
                gv[0] = fmaf(0.5f * n0, __builtin_amdgcn_rcpf(d0 + EPS_), bv);
                gv[1] = fmaf(0.5f * n1, __builtin_amdgcn_rcpf(d1 + EPS_), bv);
                gv[2] = fmaf(0.5f * n2, __builtin_amdgcn_rcpf(d2 + EPS_), bv);
                gv[3] = fmaf(0.5f * n3, __builtin_amdgcn_rcpf(d3 + EPS_), bv);
                qv[0] = d0 * i0; qv[1] = d1 * i1; qv[2] = d2 * i0; qv[3] = d3 * i1;

                const int c0 = h4 + (k << 2);
                __builtin_nontemporal_store(gv, (f4_t*)(o0 + c0));
                __builtin_nontemporal_store(qv, (f4_t*)(o1 + c0));
            }
        }
#undef VAL
    };

    // ---- 3-phase pipeline ----
    stage_rows(0, 3);                 // fused rows f0..f0+2
    __syncthreads();
    stage_rows(3, NRLDS);             // fused rows f0+3..f0+4 (guarded)
    consume_quarter(0);               // output rows 8G..8G+3 (fused 0..2)
    __syncthreads();
    consume_quarter(1);               // output rows 8G+4..8G+7 (fused 2..4)
}

extern "C" void kernel_launch(void* const* d_in, const int* in_sizes, int n_in,
                              void* d_out, int out_size, void* d_ws, size_t ws_size,
                              hipStream_t stream) {
    const float* d    = (const float*)d_in[0];
    const float* cd   = (const float*)d_in[1];
    const float* gy   = (const float*)d_in[2];
    const float* cgy  = (const float*)d_in[3];
    const float* wpr  = (const float*)d_in[4];
    const float* swr  = (const float*)d_in[5];
    const float* bias = (const float*)d_in[6];
    float* out = (float*)d_out;

    dim3 grid(44, B_ * C_);   // 44 groups of 8 output rows x 64 planes
    structn_pipe8<<<grid, NTH, 0, stream>>>(d, cd, gy, cgy, wpr, swr, bias, out);
}

// Round 12
// 70.597 us; speedup vs baseline: 1.0848x; 1.0848x over previous
//
#include <hip/hip_runtime.h>
#include <math.h>

// Problem constants
#define B_   2
#define C_   32
#define H_   176
#define W_   608
#define HO_  351
#define WO_  1215
#define PLANE_O (HO_ * WO_)          // 426465
#define OUT1_O  (B_ * C_ * PLANE_O)  // 27293760 (mult of 4 -> same alignment)
#define EPS_ 1e-20f
#define NTH  512
#define W4   (W_ / 4)                // 152 float4 per input row
#define HW_  304                     // half-row length (col-parity split)
#define NRLDS 9                      // fused rows staged per block

typedef float f4_t __attribute__((ext_vector_type(4)));
typedef float f2_t __attribute__((ext_vector_type(2)));

__device__ __forceinline__ float softplus_f(float x) {
    return fmaxf(x, 0.0f) + log1pf(expf(-fabsf(x)));
}

// Block = (16-output-row group G, plane). 8 waves, 43.8 KB LDS (R10 tile).
// 4-phase wave-specialized pipeline:
//   P0: all stage fused 0..3            | P1: w0-5 consume rows 0..5  || w6-7 stage 4..6
//   P2: w0-5 consume rows 6..11 || w6-7 stage 7..8 | P3: all consume rows 12..15
// NT stores (measured +14us vs cached: keeps inputs L3-resident across replays).
extern "C" __global__ __launch_bounds__(NTH, 6)
void structn_ws(const float* __restrict__ d,
                const float* __restrict__ cd,
                const float* __restrict__ gy,
                const float* __restrict__ cgy,
                const float* __restrict__ wpr,
                const float* __restrict__ swr,
                const float* __restrict__ bias,
                float* __restrict__ out)
{
    __shared__ float s_nE[NRLDS * HW_];   // cgy_f*gy_f, even input cols
    __shared__ float s_nO[NRLDS * HW_];   // odd cols
    __shared__ float s_cE[NRLDS * HW_];   // cgy_f, even cols
    __shared__ float s_cO[NRLDS * HW_];   // odd cols

    const int G     = blockIdx.x;     // 22 groups of 16 output rows
    const int plane = blockIdx.y;     // 64 planes
    const int c     = plane & (C_ - 1);

    // ---- per-channel constants (wave-uniform, in-block) ----
    float sw[9];
#pragma unroll
    for (int k = 0; k < 9; ++k) sw[k] = softplus_f(swr[c * 9 + k]);
    const float wp      = softplus_f(wpr[c]);
    const float inv_wp1 = 1.0f / (wp + 1.0f);
    const float bv      = bias[c];
    const float icd_ee  = 1.0f / (sw[4] + EPS_);
    const float icd_eo  = 1.0f / (sw[3] + sw[5] + EPS_);
    const float icd_oe  = 1.0f / (sw[1] + sw[7] + EPS_);
    const float icd_oo  = 1.0f / (sw[0] + sw[2] + sw[6] + sw[8] + EPS_);

    const int f0 = G * 8;             // first fused row of this block

    const int pbase = plane * (H_ * W_);
    const float* __restrict__ dP  = d   + pbase;
    const float* __restrict__ cdP = cd  + pbase;
    const float* __restrict__ gyP = gy  + pbase;
    const float* __restrict__ cgP = cgy + pbase;

    // ---- staging of local fused rows [j0, j1) by threads tid,tid+tstep,... ----
    auto stage_rows = [&](int j0, int j1, int tid, int tstep) {
        const int j1c = min(j1, H_ - f0);
        const int ntask = (j1c > j0) ? (j1c - j0) * W4 : 0;
        for (int idx = tid; idx < ntask; idx += tstep) {
            const int rf = j0 + idx / W4;
            const int iw = (idx - (rf - j0) * W4) << 2;
            const int iy = f0 + rf;
            const int up = (iy == 0)      ? (H_ - 1) : iy - 1;   // d wraps
            const int dn = (iy == H_ - 1) ? 0        : iy + 1;
            const float mu = (iy > 0)      ? 1.0f : 0.0f;
            const float md = (iy < H_ - 1) ? 1.0f : 0.0f;

            const f4_t du = *(const f4_t*)(dP  + up * W_ + iw);
            const f4_t dd = *(const f4_t*)(dP  + dn * W_ + iw);
            const f4_t cu = *(const f4_t*)(cdP + up * W_ + iw);
            const f4_t cn = *(const f4_t*)(cdP + dn * W_ + iw);
            const f4_t gg = *(const f4_t*)(gyP + iy * W_ + iw);
            const f4_t cg = *(const f4_t*)(cgP + iy * W_ + iw);

            f4_t sn4, sc4;
#pragma unroll
            for (int e = 0; e < 4; ++e) {
                const float cuv = cu[e] * mu;
                const float cnv = cn[e] * md;
                const float cfd = cuv * cuv;
                const float rs  = __builtin_amdgcn_rcpf(fmaf(cuv, du[e], cnv * dd[e]));
                const float gfd = 0.5f * (dd[e] - du[e]) * (cuv + cnv) * rs;
                const float num = fmaf(wp * cg[e], gg[e], cfd * gfd);
                const float den = fmaf(wp, cg[e], cfd);
                sn4[e] = num * inv_wp1;
                sc4[e] = den * inv_wp1;
            }
            const int eo = rf * HW_ + (iw >> 1);   // even -> 8B aligned
            f2_t v;
            v[0] = sn4[0]; v[1] = sn4[2];  *(f2_t*)(s_nE + eo) = v;
            v[0] = sn4[1]; v[1] = sn4[3];  *(f2_t*)(s_nO + eo) = v;
            v[0] = sc4[0]; v[1] = sc4[2];  *(f2_t*)(s_cE + eo) = v;
            v[0] = sc4[1]; v[1] = sc4[3];  *(f2_t*)(s_cO + eo) = v;
        }
    };

    const int w    = threadIdx.x >> 6;
    const int lane = threadIdx.x & 63;

    // ---- consume output row (local oyl), chunks k = kbase+lane', step kstep ----
    auto consume_row = [&](int oyl, int kbase, int kstep) {
        const int oy = G * 16 + oyl;
        if (oy >= HO_) return;

        const int p   = oyl & 1;       // row parity (G*16 even)
        const int lrA = oyl >> 1;      // local fused row (A)

        const int ro0 = plane * PLANE_O + oy * WO_;
        float* __restrict__ o0 = out + ro0;
        float* __restrict__ o1 = out + OUT1_O + ro0;

        const int hd = (4 - (ro0 & 3)) & 3;   // head scalars to 16B alignment
        const int n4 = (WO_ - hd) >> 2;       // aligned float4 chunks
        const int q  = hd & 1;
        const int r  = (hd >> 1) & 1;

        const float icdC = p ? icd_oe : icd_ee;
        const float icdO = p ? icd_oo : icd_eo;
        const float i0 = q ? icdO : icdC;
        const float i1 = q ? icdC : icdO;

        const float* __restrict__ nAE = s_nE + lrA * HW_;
        const float* __restrict__ nAO = s_nO + lrA * HW_;
        const float* __restrict__ cAE = s_cE + lrA * HW_;
        const float* __restrict__ cAO = s_cO + lrA * HW_;

#define VAL(E, O, j) (((j) & 1) ? (O)[((j) - 1) >> 1] : (E)[(j) >> 1])
        if (p == 0) {
            if (kbase == 0 && lane < 3) {
                const int ox = (lane < hd) ? lane : (hd + (n4 << 2) + lane - hd);
                float den, nom, icd;
                if ((ox & 1) == 0) {
                    const int j = ox >> 1;
                    den = VAL(cAE, cAO, j) * sw[4];
                    nom = VAL(nAE, nAO, j) * sw[4];
                    icd = icd_ee;
                } else {
                    const int j = (ox - 1) >> 1;
                    den = VAL(cAE, cAO, j) * sw[5] + VAL(cAE, cAO, j + 1) * sw[3];
                    nom = VAL(nAE, nAO, j) * sw[5] + VAL(nAE, nAO, j + 1) * sw[3];
                    icd = icd_eo;
                }
                o0[ox] = fmaf(0.5f * nom, __builtin_amdgcn_rcpf(den + EPS_), bv);
                o1[ox] = den * icd;
            }
            const float* pa0 = r ? nAO : nAE;
            const float* pa1 = r ? nAE + 1 : nAO;
            const float* pa2 = r ? nAO + 1 : nAE + 1;
            const float* px0 = r ? cAO : cAE;
            const float* px1 = r ? cAE + 1 : cAO;
            const float* px2 = r ? cAO + 1 : cAE + 1;

            for (int k = kbase + lane; k < n4; k += kstep) {
                const float a0 = pa0[k], a1 = pa1[k], a2 = pa2[k];
                const float x0 = px0[k], x1 = px1[k], x2 = px2[k];
                const float dC0 = x0 * sw[4], dC1 = x1 * sw[4], dC2 = x2 * sw[4];
                const float nC0 = a0 * sw[4], nC1 = a1 * sw[4], nC2 = a2 * sw[4];
                const float dF0 = x0 * sw[5] + x1 * sw[3];
                const float dF1 = x1 * sw[5] + x2 * sw[3];
                const float nF0 = a0 * sw[5] + a1 * sw[3];
                const float nF1 = a1 * sw[5] + a2 * sw[3];

                const float d0 = q ? dF0 : dC0, n0 = q ? nF0 : nC0;
                const float d1 = q ? dC1 : dF0, n1 = q ? nC1 : nF0;
                const float d2 = q ? dF1 : dC1, n2 = q ? nF1 : nC1;
                const float d3 = q ? dC2 : dF1, n3 = q ? nC2 : nF1;

                f4_t gv, qv;
                gv[0] = fmaf(0.5f * n0, __builtin_amdgcn_rcpf(d0 + EPS_), bv);
                gv[1] = fmaf(0.5f * n1, __builtin_amdgcn_rcpf(d1 + EPS_), bv);
                gv[2] = fmaf(0.5f * n2, __builtin_amdgcn_rcpf(d2 + EPS_), bv);
                gv[3] = fmaf(0.5f * n3, __builtin_amdgcn_rcpf(d3 + EPS_), bv);
                qv[0] = d0 * i0; qv[1] = d1 * i1; qv[2] = d2 * i0; qv[3] = d3 * i1;

                const int c0 = hd + (k << 2);
                __builtin_nontemporal_store(gv, (f4_t*)(o0 + c0));
                __builtin_nontemporal_store(qv, (f4_t*)(o1 + c0));
            }
        } else {
            const float* __restrict__ nBE = nAE + HW_;
            const float* __restrict__ nBO = nAO + HW_;
            const float* __restrict__ cBE = cAE + HW_;
            const float* __restrict__ cBO = cAO + HW_;

            if (kbase == 0 && lane < 3) {
                const int ox = (lane < hd) ? lane : (hd + (n4 << 2) + lane - hd);
                float den, nom, icd;
                if ((ox & 1) == 0) {
                    const int j = ox >> 1;
                    den = VAL(cAE, cAO, j) * sw[7] + VAL(cBE, cBO, j) * sw[1];
                    nom = VAL(nAE, nAO, j) * sw[7] + VAL(nBE, nBO, j) * sw[1];
                    icd = icd_oe;
                } else {
                    const int j = (ox - 1) >> 1;
                    den = VAL(cAE, cAO, j) * sw[8] + VAL(cAE, cAO, j + 1) * sw[6]
                        + VAL(cBE, cBO, j) * sw[2] + VAL(cBE, cBO, j + 1) * sw[0];
                    nom = VAL(nAE, nAO, j) * sw[8] + VAL(nAE, nAO, j + 1) * sw[6]
                        + VAL(nBE, nBO, j) * sw[2] + VAL(nBE, nBO, j + 1) * sw[0];
                    icd = icd_oo;
                }
                o0[ox] = fmaf(0.5f * nom, __builtin_amdgcn_rcpf(den + EPS_), bv);
                o1[ox] = den * icd;
            }

            const float* pa0 = r ? nAO : nAE;
            const float* pa1 = r ? nAE + 1 : nAO;
            const float* pa2 = r ? nAO + 1 : nAE + 1;
            const float* px0 = r ? cAO : cAE;
            const float* px1 = r ? cAE + 1 : cAO;
            const float* px2 = r ? cAO + 1 : cAE + 1;
            const float* pb0 = r ? nBO : nBE;
            const float* pb1 = r ? nBE + 1 : nBO;
            const float* pb2 = r ? nBO + 1 : nBE + 1;
            const float* py0 = r ? cBO : cBE;
            const float* py1 = r ? cBE + 1 : cBO;
            const float* py2 = r ? cBO + 1 : cBE + 1;

            for (int k = kbase + lane; k < n4; k += kstep) {
                const float a0 = pa0[k], a1 = pa1[k], a2 = pa2[k];
                const float x0 = px0[k], x1 = px1[k], x2 = px2[k];
                const float b0 = pb0[k], b1 = pb1[k], b2 = pb2[k];
                const float y0 = py0[k], y1 = py1[k], y2 = py2[k];

                const float dC0 = x0 * sw[7] + y0 * sw[1];
                const float dC1 = x1 * sw[7] + y1 * sw[1];
                const float dC2 = x2 * sw[7] + y2 * sw[1];
                const float nC0 = a0 * sw[7] + b0 * sw[1];
                const float nC1 = a1 * sw[7] + b1 * sw[1];
                const float nC2 = a2 * sw[7] + b2 * sw[1];
                const float dF0 = x0 * sw[8] + x1 * sw[6] + y0 * sw[2] + y1 * sw[0];
                const float dF1 = x1 * sw[8] + x2 * sw[6] + y1 * sw[2] + y2 * sw[0];
                const float nF0 = a0 * sw[8] + a1 * sw[6] + b0 * sw[2] + b1 * sw[0];
                const float nF1 = a1 * sw[8] + a2 * sw[6] + b1 * sw[2] + b2 * sw[0];

                const float d0 = q ? dF0 : dC0, n0 = q ? nF0 : nC0;
                const float d1 = q ? dC1 : dF0, n1 = q ? nC1 : nF0;
                const float d2 = q ? dF1 : dC1, n2 = q ? nF1 : nC1;
                const float d3 = q ? dC2 : dF1, n3 = q ? nC2 : nF1;

                f4_t gv, qv;
                gv[0] = fmaf(0.5f * n0, __builtin_amdgcn_rcpf(d0 + EPS_), bv);
                gv[1] = fmaf(0.5f * n1, __builtin_amdgcn_rcpf(d1 + EPS_), bv);
                gv[2] = fmaf(0.5f * n2, __builtin_amdgcn_rcpf(d2 + EPS_), bv);
                gv[3] = fmaf(0.5f * n3, __builtin_amdgcn_rcpf(d3 + EPS_), bv);
                qv[0] = d0 * i0; qv[1] = d1 * i1; qv[2] = d2 * i0; qv[3] = d3 * i1;

                const int c0 = hd + (k << 2);
                __builtin_nontemporal_store(gv, (f4_t*)(o0 + c0));
                __builtin_nontemporal_store(qv, (f4_t*)(o1 + c0));
            }
        }
#undef VAL
    };

    // ---- 4-phase wave-specialized pipeline ----
    stage_rows(0, 4, threadIdx.x, NTH);            // fused 0..3 (rows 0..5 dep)
    __syncthreads();
    if (w < 6) consume_row(w, 0, 64);              // rows 0..5
    else       stage_rows(4, 7, threadIdx.x - 384, 128);   // fused 4..6
    __syncthreads();
    if (w < 6) consume_row(6 + w, 0, 64);          // rows 6..11 (need fused <=6)
    else       stage_rows(7, 9, threadIdx.x - 384, 128);   // fused 7..8
    __syncthreads();
    consume_row(12 + (w >> 1), 64 * (w & 1), 128); // rows 12..15 (need fused <=8)
}

extern "C" void kernel_launch(void* const* d_in, const int* in_sizes, int n_in,
                              void* d_out, int out_size, void* d_ws, size_t ws_size,
                              hipStream_t stream) {
    const float* d    = (const float*)d_in[0];
    const float* cd   = (const float*)d_in[1];
    const float* gy   = (const float*)d_in[2];
    const float* cgy  = (const float*)d_in[3];
    const float* wpr  = (const float*)d_in[4];
    const float* swr  = (const float*)d_in[5];
    const float* bias = (const float*)d_in[6];
    float* out = (float*)d_out;

    dim3 grid(22, B_ * C_);   // 22 groups of 16 output rows x 64 planes
    structn_ws<<<grid, NTH, 0, stream>>>(d, cd, gy, cgy, wpr, swr, bias, out);
}

// Round 14
// 68.693 us; speedup vs baseline: 1.1148x; 1.0277x over previous
//
#include <hip/hip_runtime.h>
#include <math.h>

// Problem constants
#define B_   2
#define C_   32
#define H_   176
#define W_   608
#define HO_  351
#define WO_  1215
#define PLANE_O (HO_ * WO_)          // 426465
#define OUT1_O  (B_ * C_ * PLANE_O)  // 27293760 (mult of 4 -> same alignment)
#define EPS_ 1e-20f
#define NTH  512
#define W4   (W_ / 4)                // 152 float4 per input row
#define HW_  304                     // half-row length (col-parity split)
#define NRLDS 9                      // fused rows staged per block

typedef float f4_t __attribute__((ext_vector_type(4)));
typedef float f2_t __attribute__((ext_vector_type(2)));

__device__ __forceinline__ float softplus_f(float x) {
    return fmaxf(x, 0.0f) + log1pf(expf(-fabsf(x)));
}

// Block = (16-output-row group G, plane). 8 waves. (Measured best: R10, 68.7us)
// Fused rows f0..f0+8 staged into a 9-row parity-split LDS buffer.
// 3-phase pipeline: stage(0..4); bar; stage(5..8) || consume(half0); bar;
// consume(half1). Middle phase mixes HBM reads (stage) with NT writes
// (consume). NT stores: +14us vs cached (A/B R6 vs R8).
extern "C" __global__ __launch_bounds__(NTH, 6)
void structn_pipe(const float* __restrict__ d,
                  const float* __restrict__ cd,
                  const float* __restrict__ gy,
                  const float* __restrict__ cgy,
                  const float* __restrict__ wpr,
                  const float* __restrict__ swr,
                  const float* __restrict__ bias,
                  float* __restrict__ out)
{
    __shared__ float s_nE[NRLDS * HW_];   // cgy_f*gy_f, even input cols
    __shared__ float s_nO[NRLDS * HW_];   // odd cols
    __shared__ float s_cE[NRLDS * HW_];   // cgy_f, even cols
    __shared__ float s_cO[NRLDS * HW_];   // odd cols

    const int G     = blockIdx.x;     // 22 groups of 16 output rows
    const int plane = blockIdx.y;     // 64 planes
    const int c     = plane & (C_ - 1);

    // ---- per-channel constants (wave-uniform, in-block) ----
    float sw[9];
#pragma unroll
    for (int k = 0; k < 9; ++k) sw[k] = softplus_f(swr[c * 9 + k]);
    const float wp      = softplus_f(wpr[c]);
    const float inv_wp1 = 1.0f / (wp + 1.0f);
    const float bv      = bias[c];
    const float icd_ee  = 1.0f / (sw[4] + EPS_);
    const float icd_eo  = 1.0f / (sw[3] + sw[5] + EPS_);
    const float icd_oe  = 1.0f / (sw[1] + sw[7] + EPS_);
    const float icd_oo  = 1.0f / (sw[0] + sw[2] + sw[6] + sw[8] + EPS_);

    const int f0 = G * 8;             // first fused row of this block

    const int pbase = plane * (H_ * W_);
    const float* __restrict__ dP  = d   + pbase;
    const float* __restrict__ cdP = cd  + pbase;
    const float* __restrict__ gyP = gy  + pbase;
    const float* __restrict__ cgP = cgy + pbase;

    // ---- staging of local fused rows [j0, j1) ----
    auto stage_rows = [&](int j0, int j1) {
        const int ntask = (j1 - j0) * W4;
        for (int idx = threadIdx.x; idx < ntask; idx += NTH) {
            const int rf = j0 + idx / W4;
            const int iw = (idx - (rf - j0) * W4) << 2;
            const int iy = f0 + rf;
            const int up = (iy == 0)      ? (H_ - 1) : iy - 1;   // d wraps
            const int dn = (iy == H_ - 1) ? 0        : iy + 1;
            const float mu = (iy > 0)      ? 1.0f : 0.0f;
            const float md = (iy < H_ - 1) ? 1.0f : 0.0f;

            const f4_t du = *(const f4_t*)(dP  + up * W_ + iw);
            const f4_t dd = *(const f4_t*)(dP  + dn * W_ + iw);
            const f4_t cu = *(const f4_t*)(cdP + up * W_ + iw);
            const f4_t cn = *(const f4_t*)(cdP + dn * W_ + iw);
            const f4_t gg = *(const f4_t*)(gyP + iy * W_ + iw);
            const f4_t cg = *(const f4_t*)(cgP + iy * W_ + iw);

            f4_t sn4, sc4;
#pragma unroll
            for (int e = 0; e < 4; ++e) {
                const float cuv = cu[e] * mu;
                const float cnv = cn[e] * md;
                const float cfd = cuv * cuv;
                const float rs  = __builtin_amdgcn_rcpf(fmaf(cuv, du[e], cnv * dd[e]));
                const float gfd = 0.5f * (dd[e] - du[e]) * (cuv + cnv) * rs;
                const float num = fmaf(wp * cg[e], gg[e], cfd * gfd);
                const float den = fmaf(wp, cg[e], cfd);
                sn4[e] = num * inv_wp1;
                sc4[e] = den * inv_wp1;
            }
            const int eo = rf * HW_ + (iw >> 1);   // even -> 8B aligned
            f2_t v;
            v[0] = sn4[0]; v[1] = sn4[2];  *(f2_t*)(s_nE + eo) = v;
            v[0] = sn4[1]; v[1] = sn4[3];  *(f2_t*)(s_nO + eo) = v;
            v[0] = sc4[0]; v[1] = sc4[2];  *(f2_t*)(s_cE + eo) = v;
            v[0] = sc4[1]; v[1] = sc4[3];  *(f2_t*)(s_cO + eo) = v;
        }
    };

    const int w    = threadIdx.x >> 6;
    const int lane = threadIdx.x & 63;

    // ---- consume one half (h = 0 or 1): wave w -> output row 16G + 8h + w ----
    auto consume_half = [&](int h) {
        const int oy = G * 16 + 8 * h + w;
        if (oy >= HO_) return;

        const int p   = w & 1;              // row parity (16G+8h is even)
        const int lrA = 4 * h + (w >> 1);   // local fused row (A)

        const int ro0 = plane * PLANE_O + oy * WO_;
        float* __restrict__ o0 = out + ro0;
        float* __restrict__ o1 = out + OUT1_O + ro0;

        const int h4 = (4 - (ro0 & 3)) & 3;   // head scalars to 16B alignment
        const int n4 = (WO_ - h4) >> 2;       // aligned float4 chunks
        const int q  = h4 & 1;
        const int r  = (h4 >> 1) & 1;

        const float icdC = p ? icd_oe : icd_ee;
        const float icdO = p ? icd_oo : icd_eo;
        const float i0 = q ? icdO : icdC;
        const float i1 = q ? icdC : icdO;

        const float* __restrict__ nAE = s_nE + lrA * HW_;
        const float* __restrict__ nAO = s_nO + lrA * HW_;
        const float* __restrict__ cAE = s_cE + lrA * HW_;
        const float* __restrict__ cAO = s_cO + lrA * HW_;

#define VAL(E, O, j) (((j) & 1) ? (O)[((j) - 1) >> 1] : (E)[(j) >> 1])
        if (p == 0) {
            if (lane < 3) {
                const int ox = (lane < h4) ? lane : (h4 + (n4 << 2) + lane - h4);
                float den, nom, icd;
                if ((ox & 1) == 0) {
                    const int j = ox >> 1;
                    den = VAL(cAE, cAO, j) * sw[4];
                    nom = VAL(nAE, nAO, j) * sw[4];
                    icd = icd_ee;
                } else {
                    const int j = (ox - 1) >> 1;
                    den = VAL(cAE, cAO, j) * sw[5] + VAL(cAE, cAO, j + 1) * sw[3];
                    nom = VAL(nAE, nAO, j) * sw[5] + VAL(nAE, nAO, j + 1) * sw[3];
                    icd = icd_eo;
                }
                o0[ox] = fmaf(0.5f * nom, __builtin_amdgcn_rcpf(den + EPS_), bv);
                o1[ox] = den * icd;
            }
            const float* pa0 = r ? nAO : nAE;
            const float* pa1 = r ? nAE + 1 : nAO;
            const float* pa2 = r ? nAO + 1 : nAE + 1;
            const float* px0 = r ? cAO : cAE;
            const float* px1 = r ? cAE + 1 : cAO;
            const float* px2 = r ? cAO + 1 : cAE + 1;

            for (int k = lane; k < n4; k += 64) {
                const float a0 = pa0[k], a1 = pa1[k], a2 = pa2[k];
                const float x0 = px0[k], x1 = px1[k], x2 = px2[k];
                const float dC0 = x0 * sw[4], dC1 = x1 * sw[4], dC2 = x2 * sw[4];
                const float nC0 = a0 * sw[4], nC1 = a1 * sw[4], nC2 = a2 * sw[4];
                const float dF0 = x0 * sw[5] + x1 * sw[3];
                const float dF1 = x1 * sw[5] + x2 * sw[3];
                const float nF0 = a0 * sw[5] + a1 * sw[3];
                const float nF1 = a1 * sw[5] + a2 * sw[3];

                const float d0 = q ? dF0 : dC0, n0 = q ? nF0 : nC0;
                const float d1 = q ? dC1 : dF0, n1 = q ? nC1 : nF0;
                const float d2 = q ? dF1 : dC1, n2 = q ? nF1 : nC1;
                const float d3 = q ? dC2 : dF1, n3 = q ? nC2 : nF1;

                f4_t gv, qv;
                gv[0] = fmaf(0.5f * n0, __builtin_amdgcn_rcpf(d0 + EPS_), bv);
                gv[1] = fmaf(0.5f * n1, __builtin_amdgcn_rcpf(d1 + EPS_), bv);
                gv[2] = fmaf(0.5f * n2, __builtin_amdgcn_rcpf(d2 + EPS_), bv);
                gv[3] = fmaf(0.5f * n3, __builtin_amdgcn_rcpf(d3 + EPS_), bv);
                qv[0] = d0 * i0; qv[1] = d1 * i1; qv[2] = d2 * i0; qv[3] = d3 * i1;

                const int c0 = h4 + (k << 2);
                __builtin_nontemporal_store(gv, (f4_t*)(o0 + c0));
                __builtin_nontemporal_store(qv, (f4_t*)(o1 + c0));
            }
        } else {
            const float* __restrict__ nBE = nAE + HW_;
            const float* __restrict__ nBO = nAO + HW_;
            const float* __restrict__ cBE = cAE + HW_;
            const float* __restrict__ cBO = cAO + HW_;

            if (lane < 3) {
                const int ox = (lane < h4) ? lane : (h4 + (n4 << 2) + lane - h4);
                float den, nom, icd;
                if ((ox & 1) == 0) {
                    const int j = ox >> 1;
                    den = VAL(cAE, cAO, j) * sw[7] + VAL(cBE, cBO, j) * sw[1];
                    nom = VAL(nAE, nAO, j) * sw[7] + VAL(nBE, nBO, j) * sw[1];
                    icd = icd_oe;
                } else {
                    const int j = (ox - 1) >> 1;
                    den = VAL(cAE, cAO, j) * sw[8] + VAL(cAE, cAO, j + 1) * sw[6]
                        + VAL(cBE, cBO, j) * sw[2] + VAL(cBE, cBO, j + 1) * sw[0];
                    nom = VAL(nAE, nAO, j) * sw[8] + VAL(nAE, nAO, j + 1) * sw[6]
                        + VAL(nBE, nBO, j) * sw[2] + VAL(nBE, nBO, j + 1) * sw[0];
                    icd = icd_oo;
                }
                o0[ox] = fmaf(0.5f * nom, __builtin_amdgcn_rcpf(den + EPS_), bv);
                o1[ox] = den * icd;
            }

            const float* pa0 = r ? nAO : nAE;
            const float* pa1 = r ? nAE + 1 : nAO;
            const float* pa2 = r ? nAO + 1 : nAE + 1;
            const float* px0 = r ? cAO : cAE;
            const float* px1 = r ? cAE + 1 : cAO;
            const float* px2 = r ? cAO + 1 : cAE + 1;
            const float* pb0 = r ? nBO : nBE;
            const float* pb1 = r ? nBE + 1 : nBO;
            const float* pb2 = r ? nBO + 1 : nBE + 1;
            const float* py0 = r ? cBO : cBE;
            const float* py1 = r ? cBE + 1 : cBO;
            const float* py2 = r ? cBO + 1 : cBE + 1;

            for (int k = lane; k < n4; k += 64) {
                const float a0 = pa0[k], a1 = pa1[k], a2 = pa2[k];
                const float x0 = px0[k], x1 = px1[k], x2 = px2[k];
                const float b0 = pb0[k], b1 = pb1[k], b2 = pb2[k];
                const float y0 = py0[k], y1 = py1[k], y2 = py2[k];

                const float dC0 = x0 * sw[7] + y0 * sw[1];
                const float dC1 = x1 * sw[7] + y1 * sw[1];
                const float dC2 = x2 * sw[7] + y2 * sw[1];
                const float nC0 = a0 * sw[7] + b0 * sw[1];
                const float nC1 = a1 * sw[7] + b1 * sw[1];
                const float nC2 = a2 * sw[7] + b2 * sw[1];
                const float dF0 = x0 * sw[8] + x1 * sw[6] + y0 * sw[2] + y1 * sw[0];
                const float dF1 = x1 * sw[8] + x2 * sw[6] + y1 * sw[2] + y2 * sw[0];
                const float nF0 = a0 * sw[8] + a1 * sw[6] + b0 * sw[2] + b1 * sw[0];
                const float nF1 = a1 * sw[8] + a2 * sw[6] + b1 * sw[2] + b2 * sw[0];

                const float d0 = q ? dF0 : dC0, n0 = q ? nF0 : nC0;
                const float d1 = q ? dC1 : dF0, n1 = q ? nC1 : nF0;
                const float d2 = q ? dF1 : dC1, n2 = q ? nF1 : nC1;
                const float d3 = q ? dC2 : dF1, n3 = q ? nC2 : nF1;

                f4_t gv, qv;
                gv[0] = fmaf(0.5f * n0, __builtin_amdgcn_rcpf(d0 + EPS_), bv);
                gv[1] = fmaf(0.5f * n1, __builtin_amdgcn_rcpf(d1 + EPS_), bv);
                gv[2] = fmaf(0.5f * n2, __builtin_amdgcn_rcpf(d2 + EPS_), bv);
                gv[3] = fmaf(0.5f * n3, __builtin_amdgcn_rcpf(d3 + EPS_), bv);
                qv[0] = d0 * i0; qv[1] = d1 * i1; qv[2] = d2 * i0; qv[3] = d3 * i1;

                const int c0 = h4 + (k << 2);
                __builtin_nontemporal_store(gv, (f4_t*)(o0 + c0));
                __builtin_nontemporal_store(qv, (f4_t*)(o1 + c0));
            }
        }
#undef VAL
    };

    // ---- 3-phase pipeline ----
    stage_rows(0, 5);                       // fused rows f0..f0+4
    __syncthreads();
    stage_rows(5, min(NRLDS, H_ - f0));     // fused rows f0+5..f0+8 (guarded)
    consume_half(0);                        // overlaps with staging above
    __syncthreads();
    consume_half(1);
}

extern "C" void kernel_launch(void* const* d_in, const int* in_sizes, int n_in,
                              void* d_out, int out_size, void* d_ws, size_t ws_size,
                              hipStream_t stream) {
    const float* d    = (const float*)d_in[0];
    const float* cd   = (const float*)d_in[1];
    const float* gy   = (const float*)d_in[2];
    const float* cgy  = (const float*)d_in[3];
    const float* wpr  = (const float*)d_in[4];
    const float* swr  = (const float*)d_in[5];
    const float* bias = (const float*)d_in[6];
    float* out = (float*)d_out;

    dim3 grid(22, B_ * C_);   // 22 groups of 16 output rows x 64 planes
    structn_pipe<<<grid, NTH, 0, stream>>>(d, cd, gy, cgy, wpr, swr, bias, out);
}